// Round 7
// baseline (259.920 us; speedup 1.0000x reference)
//
#include <hip/hip_runtime.h>
#include <hip/hip_cooperative_groups.h>
#include <math.h>

namespace cg = cooperative_groups;

#define NWG 256
#define NPAIR 128
#define NITER 3
#define NBATCH 8192
#define KDIM 512
#define MSZ (512*512)
#define PLANE 65536
#define CMSZ (2*PLANE)

// ws byte offsets — peak 27,262,976 B <= proven-safe 27,271,168 (R5)
#define OFF_XBUF0   0u          // 8 MB  [B->F, G->H]
#define OFF_CHUNKH  8388608u    // 6 MB  [B->C]
#define OFF_CHUNKL  14680064u   // 6 MB  [B->C]
#define OFF_TH      20971520u   // 3 MB  [C->D]
#define OFF_TL      24117248u   // 3 MB  [C->D]
#define OFF_PH      8388608u    // 1.5MB [D->E] (alias chunkH, dead)
#define OFF_PL      9961472u    // 1.5MB [D->E]
#define OFF_BMAT    11534336u   // 1.5MB [E->H]
#define OFF_XBUF1   13107200u   // 8 MB  [F->G]
#define OFF_IBUF    13107200u   // 8 MB  [H->I] (alias xbuf1, dead)

typedef __attribute__((ext_vector_type(8))) short short8;
typedef __attribute__((ext_vector_type(4))) float floatx4;

static __device__ __forceinline__ unsigned short f2bf(float f) {
    unsigned int u = __float_as_uint(f);
    unsigned int r = (u + 0x7fffu + ((u >> 16) & 1u)) >> 16;
    return (unsigned short)r;
}
static __device__ __forceinline__ float bf2f(unsigned short h) {
    return __uint_as_float(((unsigned int)h) << 16);
}
static __device__ __forceinline__ void bsplit(float v, unsigned short &h, unsigned short &l) {
    h = f2bf(v);
    l = f2bf(v - bf2f(h));
}
static __device__ __forceinline__ void async16(const void* g, void* l) {
    __builtin_amdgcn_global_load_lds(
        (const __attribute__((address_space(1))) unsigned int*)g,
        (__attribute__((address_space(3))) unsigned int*)l, 16, 0, 0);
}

static __device__ __forceinline__ void apply2(
    float &x0r, float &x0i, float &x1r, float &x1i,
    const float4 a, const float4 b)
{
    float y0r = a.x*x0r - a.y*x0i + a.z*x1r - a.w*x1i;
    float y0i = a.x*x0i + a.y*x0r + a.z*x1i + a.w*x1r;
    float y1r = b.x*x0r - b.y*x0i + b.z*x1r - b.w*x1i;
    float y1i = b.x*x0i + b.y*x0r + b.z*x1i + b.w*x1r;
    x0r = y0r; x0i = y0i; x1r = y1r; x1i = y1i;
}

static __device__ __forceinline__ void makeCoef(float th, float ph, bool rev,
                                                float4 &ca, float4 &cb) {
    float h  = 0.5f * th;
    float sh = __sinf(h),  ch = __cosf(h);
    float sp = __sinf(ph), cp = __cosf(ph);
    float pr = -sh, pi = ch;                 // pre = i*exp(i*h)
    float qr = pr*cp - pi*sp, qi = pr*sp + pi*cp;
    float Ar = qr*sh, Ai = qi*sh, Br = pr*ch, Bi = pi*ch;
    float Cr = qr*ch, Ci = qi*ch, Dr = -pr*sh, Di = -pi*sh;
    if (!rev) { ca = make_float4(Ar,Ai,Br,Bi); cb = make_float4(Cr,Ci,Dr,Di); }
    else      { ca = make_float4(Ar,Ai,Cr,Ci); cb = make_float4(Br,Bi,Dr,Di); }
}

// ---- phase B: propagate (vb<384) + convert (all vbs) -----------------------
static __device__ void phaseProp(
    int vb, int vtid,
    const float* __restrict__ xre, const float* __restrict__ xim,
    const float* __restrict__ theta, const float* __restrict__ phi,
    const float* __restrict__ gamma,
    unsigned short* __restrict__ chunkH, unsigned short* __restrict__ chunkL,
    unsigned short* __restrict__ xbuf0)
{
    const int lane = vtid & 63, vwv = vtid >> 6;
    if (vb < 384) {
        const int grp = vb >> 4, rb = vb & 15;     // 24 groups x 16 vblocks
        const int it = grp >> 3, c = grp & 7;
        const bool rev = (c & 1);
        const int r0 = rb*16 + vwv*4;              // 4 rows per wave

        float xr[4][4], xi[4][4];
#pragma unroll
        for (int r = 0; r < 4; ++r) {
            float gc = 1.0f, gs = 0.0f;
            if (c == 7) {
                float g = gamma[it*NWG + r0 + r];
                gc = __cosf(g); gs = __sinf(g);
            }
#pragma unroll
            for (int e = 0; e < 4; ++e) {
                bool on = (4*lane + e) == (r0 + r);
                xr[r][e] = on ? gc : 0.0f;
                xi[r][e] = on ? gs : 0.0f;
            }
        }

        const float* thb = theta + (size_t)(it*NWG + c*32) * NPAIR;
        const float* phb = phi   + (size_t)(it*NWG + c*32) * NPAIR;
        int sp0 = rev ? 31 : 0;
        float2 t01 = *(const float2*)(thb + sp0*NPAIR + 2*lane);
        float2 p01 = *(const float2*)(phb + sp0*NPAIR + 2*lane);

        for (int s = 0; s < 32; ++s) {
            int sn  = (s + 1 < 32) ? s + 1 : s;
            int spn = rev ? 31 - sn : sn;
            float2 t01n = *(const float2*)(thb + spn*NPAIR + 2*lane);
            float2 p01n = *(const float2*)(phb + spn*NPAIR + 2*lane);

            float4 c0a, c0b, c1a, c1b;
            makeCoef(t01.x, p01.x, rev, c0a, c0b);
            makeCoef(t01.y, p01.y, rev, c1a, c1b);

            int sp = rev ? 31 - s : s;
            if ((sp & 1) == 0) {
#pragma unroll
                for (int r = 0; r < 4; ++r) {
                    apply2(xr[r][0], xi[r][0], xr[r][1], xi[r][1], c0a, c0b);
                    apply2(xr[r][2], xi[r][2], xr[r][3], xi[r][3], c1a, c1b);
                }
            } else {
#pragma unroll
                for (int r = 0; r < 4; ++r) {
                    float tr = __shfl_down(xr[r][0], 1, 64);
                    float ti = __shfl_down(xi[r][0], 1, 64);
                    apply2(xr[r][1], xi[r][1], xr[r][2], xi[r][2], c0a, c0b);
                    float x3r = xr[r][3], x3i = xi[r][3];
                    float y3r = c1a.x*x3r - c1a.y*x3i + c1a.z*tr - c1a.w*ti;
                    float y3i = c1a.x*x3i + c1a.y*x3r + c1a.z*ti + c1a.w*tr;
                    float ynr = c1b.x*x3r - c1b.y*x3i + c1b.z*tr - c1b.w*ti;
                    float yni = c1b.x*x3i + c1b.y*x3r + c1b.z*ti + c1b.w*tr;
                    float rr = __shfl_up(ynr, 1, 64);
                    float ri = __shfl_up(yni, 1, 64);
                    if (lane != 63) { xr[r][3] = y3r; xi[r][3] = y3i; }
                    if (lane != 0)  { xr[r][0] = rr;  xi[r][0] = ri; }
                }
            }
            t01 = t01n; p01 = p01n;
        }

        unsigned short* bh = chunkH + (size_t)grp * CMSZ;
        unsigned short* bl = chunkL + (size_t)grp * CMSZ;
#pragma unroll
        for (int r = 0; r < 4; ++r) {
            int rowIdx = r0 + r;
            ushort4 reH, reL, imH, imL;
            unsigned short h, l;
#pragma unroll
            for (int e = 0; e < 4; ++e) {
                bsplit(xr[r][e], h, l); ((unsigned short*)&reH)[e] = h; ((unsigned short*)&reL)[e] = l;
                bsplit(xi[r][e], h, l); ((unsigned short*)&imH)[e] = h; ((unsigned short*)&imL)[e] = l;
            }
            *(ushort4*)(bh + (size_t)rowIdx*256 + 4*lane)         = reH;
            *(ushort4*)(bh + PLANE + (size_t)rowIdx*256 + 4*lane) = imH;
            *(ushort4*)(bl + (size_t)rowIdx*256 + 4*lane)         = reL;
            *(ushort4*)(bl + PLANE + (size_t)rowIdx*256 + 4*lane) = imL;
        }
    }
    // convert x -> bf16 embedded rows (static partition over all 512 vbs)
    {
        int nunit, ubase;
        if (vb >= 384) { nunit = 32; ubase = (vb - 384) * 32; }
        else           { nunit = 11; ubase = 4096 + vb * 11; }
        for (int u = 0; u < nunit; ++u) {
            int unit = ubase + u;
            if (unit >= NBATCH) break;
            xbuf0[(size_t)unit * KDIM + vtid]       = f2bf(xre[(size_t)unit * NWG + vtid]);
            xbuf0[(size_t)unit * KDIM + 256 + vtid] = f2bf(xim[(size_t)unit * NWG + vtid]);
        }
    }
}

// ---- compose: C = Sa * Sb^T (complex, real-embedded at staging) ------------
static __device__ void composeTile(
    const unsigned short* __restrict__ srcH, const unsigned short* __restrict__ srcL,
    unsigned short* __restrict__ outH, unsigned short* __restrict__ outL,
    unsigned short* __restrict__ bmat, int level, int z, int bx, int by,
    int vtid, unsigned short* smem)
{
    unsigned short* sAh = smem;
    unsigned short* sAl = smem + 2048;
    unsigned short* sBh = smem + 4096;
    unsigned short* sBl = smem + 6144;
    int ai, bi;
    if (level == 0) {
        const int amap[4] = {0,3,4,7}, bmap[4] = {1,2,5,6};
        int it = z >> 2, j = z & 3;
        ai = it*8 + amap[j]; bi = it*8 + bmap[j];
    } else if (level == 1) {
        int it = z >> 1, wh = z & 1;
        ai = it*4 + (wh ? 3 : 0); bi = it*4 + (wh ? 2 : 1);
    } else {
        ai = 2*z + 1; bi = 2*z;
    }
    const int lane = vtid & 63, wv = vtid >> 6;
    const int quad = lane >> 4, l16 = lane & 15;
    const int m0 = bx * 64;                 // embedded rows [0,512)
    const int n0 = by * 64;                 // complex cols [0,256)
    const bool isA = (wv < 2);
    const unsigned short* mat = ((wv & 1) ? srcL : srcH) + (size_t)(isA ? ai : bi) * CMSZ;
    unsigned short* dst = (wv==0)?sAh:(wv==1)?sAl:(wv==2)?sBh:sBl;
    const int l2 = lane >> 2, kq = (lane & 3) * 8;
    const int rowb = isA ? ((m0 < 256) ? m0 : m0 - 256) : n0;

    floatx4 acc[4] = {};
    for (int kt = 0; kt < KDIM; kt += 32) {
        int po; bool neg = false;
        if (kt < 256) po = (isA && m0 >= 256) ? PLANE : 0;
        else {
            if (isA) { if (m0 < 256) { po = PLANE; neg = true; } else po = 0; }
            else po = PLANE;
        }
        int keff = (kt < 256 ? kt : kt - 256) + kq;
        const unsigned short* sp_ = mat + po;

        __syncthreads();
#pragma unroll
        for (int i = 0; i < 4; ++i) {
            int rl = i*16 + l2;
            uint4 v = *(const uint4*)(sp_ + (size_t)(rowb + rl)*256 + keff);
            if (neg) { v.x ^= 0x80008000u; v.y ^= 0x80008000u; v.z ^= 0x80008000u; v.w ^= 0x80008000u; }
            *(uint4*)(dst + rl*32 + kq) = v;
        }
        __syncthreads();

        short8 ah = *(const short8*)&sAh[(16*wv + l16)*32 + quad*8];
        short8 al = *(const short8*)&sAl[(16*wv + l16)*32 + quad*8];
#pragma unroll
        for (int ni = 0; ni < 4; ++ni) {
            short8 bh = *(const short8*)&sBh[(16*ni + l16)*32 + quad*8];
            short8 bl = *(const short8*)&sBl[(16*ni + l16)*32 + quad*8];
            acc[ni] = __builtin_amdgcn_mfma_f32_16x16x32_bf16(ah, bh, acc[ni], 0,0,0);
            acc[ni] = __builtin_amdgcn_mfma_f32_16x16x32_bf16(ah, bl, acc[ni], 0,0,0);
            acc[ni] = __builtin_amdgcn_mfma_f32_16x16x32_bf16(al, bh, acc[ni], 0,0,0);
        }
    }
#pragma unroll
    for (int ni = 0; ni < 4; ++ni)
#pragma unroll
        for (int rg = 0; rg < 4; ++rg) {
            int r = m0 + 16*wv + quad*4 + rg;
            int cc = n0 + 16*ni + l16;
            float v = acc[ni][rg];
            if (level < 2) {
                unsigned short h, l; bsplit(v, h, l);
                size_t off = (size_t)z*CMSZ + ((r < 256) ? ((size_t)r*256 + cc)
                                                         : (PLANE + (size_t)(r-256)*256 + cc));
                outH[off] = h; outL[off] = l;
            } else {
                unsigned short* bm = bmat + (size_t)z*MSZ;
                if (r < 256) {
                    unsigned short h = f2bf(v);
                    bm[(size_t)r*KDIM + cc] = h;
                    bm[(size_t)(r+256)*KDIM + cc + 256] = h;
                } else {
                    bm[(size_t)r*KDIM + cc] = f2bf(v);
                    bm[(size_t)(r-256)*KDIM + cc + 256] = f2bf(-v);
                }
            }
        }
}

// ---- batch GEMM tile: out[b][n] = sum_k x[b][k]*Bm[n][k], 64x128 tile ------
static __device__ void gemmTile(
    const unsigned short* __restrict__ A, const unsigned short* __restrict__ Bm,
    int mode, unsigned short* __restrict__ xout, float* __restrict__ Iout,
    int bx, int by, int vtid, unsigned short* smem)
{
    unsigned short* sA = smem;             // 64*32
    unsigned short* sB = smem + 2048;      // 128*32
    const int lane = vtid & 63, wv = vtid >> 6;
    const int quad = lane >> 4, l16 = lane & 15;
    const int m0 = bx * 64, n0 = by * 64;
    const int trowb = lane >> 2, tcol = (lane & 3) * 8;

    floatx4 acc[8] = {};
    for (int kt = 0; kt < KDIM; kt += 32) {
        __syncthreads();
        async16(A + (size_t)(m0 + 16*wv + trowb)*KDIM + kt + tcol,
                &sA[wv*512 + lane*8]);
#pragma unroll
        for (int j = 0; j < 2; ++j) {
            int trow = 32*wv + 16*j + trowb;
            int grow = (trow < 64) ? (n0 + trow) : (n0 + trow + 192);
            async16(Bm + (size_t)grow*KDIM + kt + tcol,
                    &sB[(32*wv + 16*j)*32 + lane*8]);
        }
        __syncthreads();
        short8 a = *(const short8*)&sA[(16*wv + l16)*32 + quad*8];
#pragma unroll
        for (int ni = 0; ni < 8; ++ni) {
            short8 b = *(const short8*)&sB[(16*ni + l16)*32 + quad*8];
            acc[ni] = __builtin_amdgcn_mfma_f32_16x16x32_bf16(a, b, acc[ni], 0,0,0);
        }
    }
#pragma unroll
    for (int ni = 0; ni < 4; ++ni)
#pragma unroll
        for (int rg = 0; rg < 4; ++rg) {
            int row = m0 + 16*wv + quad*4 + rg;
            int cc  = n0 + 16*ni + l16;
            float yr = acc[ni][rg], yi = acc[ni+4][rg];
            if (mode == 2) {
                Iout[(size_t)row*256 + cc] = yr*yr + yi*yi;
            } else {
                float I = yr*yr + yi*yi;
                float phase = 0.078539816339744831f * I + 1.5707963267948966f;
                float sp, cp; __sincosf(phase, &sp, &cp);
                float f = 0.94868329805051381f * cp;
                xout[(size_t)row*KDIM + cc]       = f2bf(f*(cp*yr + sp*yi));
                xout[(size_t)row*KDIM + cc + 256] = f2bf(f*(cp*yi - sp*yr));
            }
        }
}

static __device__ void phaseFinal(int vb, int vtid,
                                  const float* __restrict__ Ibuf,
                                  float* __restrict__ out)
{
    const int lane = vtid & 63, vwv = vtid >> 6;
#pragma unroll
    for (int rep = 0; rep < 4; ++rep) {
        int row = vb*16 + vwv*4 + rep;
        float4 v = *(const float4*)(Ibuf + (size_t)row * 256 + 4*lane);
        float ss = v.x*v.x + v.y*v.y + v.z*v.z + v.w*v.w;
#pragma unroll
        for (int d = 1; d < 64; d <<= 1) ss += __shfl_xor(ss, d, 64);
        float inv = 1.0f / fmaxf(sqrtf(ss), 1e-12f);
        float* o = out + (size_t)row * 10;
        if (lane == 0)      { o[0]=v.x*inv; o[1]=v.y*inv; o[2]=v.z*inv; o[3]=v.w*inv; }
        else if (lane == 1) { o[4]=v.x*inv; o[5]=v.y*inv; o[6]=v.z*inv; o[7]=v.w*inv; }
        else if (lane == 2) { o[8]=v.x*inv; o[9]=v.y*inv; }
    }
}

static __device__ __forceinline__ void do_phase(
    int ph, int vb, int vtid, unsigned short* smem,
    const float* xre, const float* xim, const float* theta,
    const float* phi, const float* gamma, char* ws, float* out)
{
    unsigned short* xbuf0  = (unsigned short*)(ws + OFF_XBUF0);
    unsigned short* chunkH = (unsigned short*)(ws + OFF_CHUNKH);
    unsigned short* chunkL = (unsigned short*)(ws + OFF_CHUNKL);
    unsigned short* TH     = (unsigned short*)(ws + OFF_TH);
    unsigned short* TL     = (unsigned short*)(ws + OFF_TL);
    unsigned short* PH     = (unsigned short*)(ws + OFF_PH);
    unsigned short* PL     = (unsigned short*)(ws + OFF_PL);
    unsigned short* bmat   = (unsigned short*)(ws + OFF_BMAT);
    unsigned short* xbuf1  = (unsigned short*)(ws + OFF_XBUF1);
    float*          Ibuf   = (float*)(ws + OFF_IBUF);

    switch (ph) {
    case 0: phaseProp(vb, vtid, xre, xim, theta, phi, gamma, chunkH, chunkL, xbuf0); break;
    case 1: if (vb < 384) composeTile(chunkH, chunkL, TH, TL, nullptr, 0,
                                      vb >> 5, (vb >> 2) & 7, vb & 3, vtid, smem); break;
    case 2: if (vb < 192) composeTile(TH, TL, PH, PL, nullptr, 1,
                                      vb >> 5, (vb >> 2) & 7, vb & 3, vtid, smem); break;
    case 3: if (vb < 96)  composeTile(PH, PL, nullptr, nullptr, bmat, 2,
                                      vb >> 5, (vb >> 2) & 7, vb & 3, vtid, smem); break;
    case 4: gemmTile(xbuf0, bmat,         0, xbuf1, nullptr, vb >> 2, vb & 3, vtid, smem); break;
    case 5: gemmTile(xbuf1, bmat + MSZ,   1, xbuf0, nullptr, vb >> 2, vb & 3, vtid, smem); break;
    case 6: gemmTile(xbuf0, bmat + 2*MSZ, 2, nullptr, Ibuf,  vb >> 2, vb & 3, vtid, smem); break;
    case 7: phaseFinal(vb, vtid, Ibuf, out); break;
    }
}

// 256 blocks x 512 threads; each block = two 256-thread virtual blocks.
// All phase vb-ranges are even, so both halves always agree on barrier paths.
__global__ __launch_bounds__(512, 2) void mega_kernel(
    const float* __restrict__ xre, const float* __restrict__ xim,
    const float* __restrict__ theta, const float* __restrict__ phi,
    const float* __restrict__ gamma, char* __restrict__ ws,
    float* __restrict__ out)
{
    __shared__ unsigned short smem_all[16384];   // 32 KB: 16 KB per half
    cg::grid_group grid = cg::this_grid();
    const int half = threadIdx.x >> 8;
    const int vtid = threadIdx.x & 255;
    const int vb   = blockIdx.x * 2 + half;
    unsigned short* smem = smem_all + half * 8192;

    for (int ph = 0; ph < 8; ++ph) {
        do_phase(ph, vb, vtid, smem, xre, xim, theta, phi, gamma, ws, out);
        if (ph < 7) grid.sync();
    }
}

// fallback: one phase per plain launch (stream order provides the sync)
__global__ __launch_bounds__(512, 2) void phase_kernel(
    int ph,
    const float* __restrict__ xre, const float* __restrict__ xim,
    const float* __restrict__ theta, const float* __restrict__ phi,
    const float* __restrict__ gamma, char* __restrict__ ws,
    float* __restrict__ out)
{
    __shared__ unsigned short smem_all[16384];
    const int half = threadIdx.x >> 8;
    const int vtid = threadIdx.x & 255;
    const int vb   = blockIdx.x * 2 + half;
    do_phase(ph, vb, vtid, smem_all + half * 8192, xre, xim, theta, phi, gamma, ws, out);
}

extern "C" void kernel_launch(void* const* d_in, const int* in_sizes, int n_in,
                              void* d_out, int out_size, void* d_ws, size_t ws_size,
                              hipStream_t stream)
{
    const float* x_real = (const float*)d_in[0];
    const float* x_imag = (const float*)d_in[1];
    const float* theta  = (const float*)d_in[2];
    const float* phi    = (const float*)d_in[3];
    const float* gamma  = (const float*)d_in[4];
    char* ws = (char*)d_ws;
    float* outp = (float*)d_out;

    // deterministic host-side co-residency check (same result every call)
    int maxBlocks = 0;
    hipError_t qerr = hipOccupancyMaxActiveBlocksPerMultiprocessor(
        &maxBlocks, (const void*)mega_kernel, 512, 0);

    if (qerr == hipSuccess && maxBlocks >= 1) {
        void* args[] = { (void*)&x_real, (void*)&x_imag, (void*)&theta,
                         (void*)&phi, (void*)&gamma, (void*)&ws, (void*)&outp };
        hipLaunchCooperativeKernel((void*)mega_kernel, dim3(256), dim3(512),
                                   args, 0, stream);
    } else {
        for (int ph = 0; ph < 8; ++ph)
            phase_kernel<<<256, 512, 0, stream>>>(ph, x_real, x_imag, theta,
                                                  phi, gamma, ws, outp);
    }
}

// Round 8
// 215.021 us; speedup vs baseline: 1.2088x; 1.2088x over previous
//
#include <hip/hip_runtime.h>
#include <math.h>

#define NWG 256
#define NPAIR 128
#define NITER 3
#define NBATCH 8192
#define KDIM 512
#define MSZ (512*512)
#define PLANE 65536
#define CMSZ (2*PLANE)

// ws byte offsets — peak 27,262,976 B (proven safe in R7)
#define OFF_XBUF0   0u          // 8 MB  [prop->g0, g1->g2]
#define OFF_CHUNKH  8388608u    // 6 MB  [prop->c0]
#define OFF_CHUNKL  14680064u   // 6 MB  [prop->c0]
#define OFF_TH      20971520u   // 3 MB  [c0->c1]
#define OFF_TL      24117248u   // 3 MB  [c0->c1]
#define OFF_PH      8388608u    // 1.5MB [c1->c2] (alias chunkH, dead)
#define OFF_PL      9961472u    // 1.5MB [c1->c2]
#define OFF_BMAT    11534336u   // 1.5MB [c2->g2]
#define OFF_XBUF1   13107200u   // 8 MB  [g0->g1]
#define OFF_IBUF    13107200u   // 8 MB  [g2->final] (alias xbuf1, dead)

typedef __attribute__((ext_vector_type(8))) short short8;
typedef __attribute__((ext_vector_type(4))) float floatx4;

static __device__ __forceinline__ unsigned short f2bf(float f) {
    unsigned int u = __float_as_uint(f);
    unsigned int r = (u + 0x7fffu + ((u >> 16) & 1u)) >> 16;
    return (unsigned short)r;
}
static __device__ __forceinline__ float bf2f(unsigned short h) {
    return __uint_as_float(((unsigned int)h) << 16);
}
static __device__ __forceinline__ void bsplit(float v, unsigned short &h, unsigned short &l) {
    h = f2bf(v);
    l = f2bf(v - bf2f(h));
}
static __device__ __forceinline__ void async16(const void* g, void* l) {
    __builtin_amdgcn_global_load_lds(
        (const __attribute__((address_space(1))) unsigned int*)g,
        (__attribute__((address_space(3))) unsigned int*)l, 16, 0, 0);
}

static __device__ __forceinline__ void apply2(
    float &x0r, float &x0i, float &x1r, float &x1i,
    const float4 a, const float4 b)
{
    float y0r = a.x*x0r - a.y*x0i + a.z*x1r - a.w*x1i;
    float y0i = a.x*x0i + a.y*x0r + a.z*x1i + a.w*x1r;
    float y1r = b.x*x0r - b.y*x0i + b.z*x1r - b.w*x1i;
    float y1i = b.x*x0i + b.y*x0r + b.z*x1i + b.w*x1r;
    x0r = y0r; x0i = y0i; x1r = y1r; x1i = y1i;
}

static __device__ __forceinline__ void makeCoef(float th, float ph, bool rev,
                                                float4 &ca, float4 &cb) {
    float h  = 0.5f * th;
    float sh = __sinf(h),  ch = __cosf(h);
    float sp = __sinf(ph), cp = __cosf(ph);
    float pr = -sh, pi = ch;                 // pre = i*exp(i*h)
    float qr = pr*cp - pi*sp, qi = pr*sp + pi*cp;
    float Ar = qr*sh, Ai = qi*sh, Br = pr*ch, Bi = pi*ch;
    float Cr = qr*ch, Ci = qi*ch, Dr = -pr*sh, Di = -pi*sh;
    if (!rev) { ca = make_float4(Ar,Ai,Br,Bi); cb = make_float4(Cr,Ci,Dr,Di); }
    else      { ca = make_float4(Ar,Ai,Cr,Ci); cb = make_float4(Br,Bi,Dr,Di); }
}

// ---- propagate (vb<384): 24 groups x 16 vbs, 32 layers, 4 rows/wave -------
// + convert x -> bf16 embedded rows (all 512 vbs, static partition)
static __device__ void phaseProp(
    int vb, int vtid,
    const float* __restrict__ xre, const float* __restrict__ xim,
    const float* __restrict__ theta, const float* __restrict__ phi,
    const float* __restrict__ gamma,
    unsigned short* __restrict__ chunkH, unsigned short* __restrict__ chunkL,
    unsigned short* __restrict__ xbuf0)
{
    const int lane = vtid & 63, vwv = vtid >> 6;
    if (vb < 384) {
        const int grp = vb >> 4, rb = vb & 15;
        const int it = grp >> 3, c = grp & 7;
        const bool rev = (c & 1);
        const int r0 = rb*16 + vwv*4;

        float xr[4][4], xi[4][4];
#pragma unroll
        for (int r = 0; r < 4; ++r) {
            float gc = 1.0f, gs = 0.0f;
            if (c == 7) {
                float g = gamma[it*NWG + r0 + r];
                gc = __cosf(g); gs = __sinf(g);
            }
#pragma unroll
            for (int e = 0; e < 4; ++e) {
                bool on = (4*lane + e) == (r0 + r);
                xr[r][e] = on ? gc : 0.0f;
                xi[r][e] = on ? gs : 0.0f;
            }
        }

        const float* thb = theta + (size_t)(it*NWG + c*32) * NPAIR;
        const float* phb = phi   + (size_t)(it*NWG + c*32) * NPAIR;
        int sp0 = rev ? 31 : 0;
        float2 t01 = *(const float2*)(thb + sp0*NPAIR + 2*lane);
        float2 p01 = *(const float2*)(phb + sp0*NPAIR + 2*lane);

        for (int s = 0; s < 32; ++s) {
            int sn  = (s + 1 < 32) ? s + 1 : s;
            int spn = rev ? 31 - sn : sn;
            float2 t01n = *(const float2*)(thb + spn*NPAIR + 2*lane);
            float2 p01n = *(const float2*)(phb + spn*NPAIR + 2*lane);

            float4 c0a, c0b, c1a, c1b;
            makeCoef(t01.x, p01.x, rev, c0a, c0b);
            makeCoef(t01.y, p01.y, rev, c1a, c1b);

            int sp = rev ? 31 - s : s;
            if ((sp & 1) == 0) {
#pragma unroll
                for (int r = 0; r < 4; ++r) {
                    apply2(xr[r][0], xi[r][0], xr[r][1], xi[r][1], c0a, c0b);
                    apply2(xr[r][2], xi[r][2], xr[r][3], xi[r][3], c1a, c1b);
                }
            } else {
#pragma unroll
                for (int r = 0; r < 4; ++r) {
                    float tr = __shfl_down(xr[r][0], 1, 64);
                    float ti = __shfl_down(xi[r][0], 1, 64);
                    apply2(xr[r][1], xi[r][1], xr[r][2], xi[r][2], c0a, c0b);
                    float x3r = xr[r][3], x3i = xi[r][3];
                    float y3r = c1a.x*x3r - c1a.y*x3i + c1a.z*tr - c1a.w*ti;
                    float y3i = c1a.x*x3i + c1a.y*x3r + c1a.z*ti + c1a.w*tr;
                    float ynr = c1b.x*x3r - c1b.y*x3i + c1b.z*tr - c1b.w*ti;
                    float yni = c1b.x*x3i + c1b.y*x3r + c1b.z*ti + c1b.w*tr;
                    float rr = __shfl_up(ynr, 1, 64);
                    float ri = __shfl_up(yni, 1, 64);
                    if (lane != 63) { xr[r][3] = y3r; xi[r][3] = y3i; }
                    if (lane != 0)  { xr[r][0] = rr;  xi[r][0] = ri; }
                }
            }
            t01 = t01n; p01 = p01n;
        }

        unsigned short* bh = chunkH + (size_t)grp * CMSZ;
        unsigned short* bl = chunkL + (size_t)grp * CMSZ;
#pragma unroll
        for (int r = 0; r < 4; ++r) {
            int rowIdx = r0 + r;
            ushort4 reH, reL, imH, imL;
            unsigned short h, l;
#pragma unroll
            for (int e = 0; e < 4; ++e) {
                bsplit(xr[r][e], h, l); ((unsigned short*)&reH)[e] = h; ((unsigned short*)&reL)[e] = l;
                bsplit(xi[r][e], h, l); ((unsigned short*)&imH)[e] = h; ((unsigned short*)&imL)[e] = l;
            }
            *(ushort4*)(bh + (size_t)rowIdx*256 + 4*lane)         = reH;
            *(ushort4*)(bh + PLANE + (size_t)rowIdx*256 + 4*lane) = imH;
            *(ushort4*)(bl + (size_t)rowIdx*256 + 4*lane)         = reL;
            *(ushort4*)(bl + PLANE + (size_t)rowIdx*256 + 4*lane) = imL;
        }
    }
    {
        int nunit, ubase;
        if (vb >= 384) { nunit = 32; ubase = (vb - 384) * 32; }
        else           { nunit = 11; ubase = 4096 + vb * 11; }
        for (int u = 0; u < nunit; ++u) {
            int unit = ubase + u;
            if (unit >= NBATCH) break;
            xbuf0[(size_t)unit * KDIM + vtid]       = f2bf(xre[(size_t)unit * NWG + vtid]);
            xbuf0[(size_t)unit * KDIM + 256 + vtid] = f2bf(xim[(size_t)unit * NWG + vtid]);
        }
    }
}

// ---- compose: C = Sa * Sb^T (complex, real-embedded at staging) ------------
static __device__ void composeTile(
    const unsigned short* __restrict__ srcH, const unsigned short* __restrict__ srcL,
    unsigned short* __restrict__ outH, unsigned short* __restrict__ outL,
    unsigned short* __restrict__ bmat, int level, int z, int bx, int by,
    int vtid, unsigned short* smem)
{
    unsigned short* sAh = smem;
    unsigned short* sAl = smem + 2048;
    unsigned short* sBh = smem + 4096;
    unsigned short* sBl = smem + 6144;
    int ai, bi;
    if (level == 0) {
        const int amap[4] = {0,3,4,7}, bmap[4] = {1,2,5,6};
        int it = z >> 2, j = z & 3;
        ai = it*8 + amap[j]; bi = it*8 + bmap[j];
    } else if (level == 1) {
        int it = z >> 1, wh = z & 1;
        ai = it*4 + (wh ? 3 : 0); bi = it*4 + (wh ? 2 : 1);
    } else {
        ai = 2*z + 1; bi = 2*z;
    }
    const int lane = vtid & 63, wv = vtid >> 6;
    const int quad = lane >> 4, l16 = lane & 15;
    const int m0 = bx * 64;
    const int n0 = by * 64;
    const bool isA = (wv < 2);
    const unsigned short* mat = ((wv & 1) ? srcL : srcH) + (size_t)(isA ? ai : bi) * CMSZ;
    unsigned short* dst = (wv==0)?sAh:(wv==1)?sAl:(wv==2)?sBh:sBl;
    const int l2 = lane >> 2, kq = (lane & 3) * 8;
    const int rowb = isA ? ((m0 < 256) ? m0 : m0 - 256) : n0;

    floatx4 acc[4] = {};
    for (int kt = 0; kt < KDIM; kt += 32) {
        int po; bool neg = false;
        if (kt < 256) po = (isA && m0 >= 256) ? PLANE : 0;
        else {
            if (isA) { if (m0 < 256) { po = PLANE; neg = true; } else po = 0; }
            else po = PLANE;
        }
        int keff = (kt < 256 ? kt : kt - 256) + kq;
        const unsigned short* sp_ = mat + po;

        __syncthreads();
#pragma unroll
        for (int i = 0; i < 4; ++i) {
            int rl = i*16 + l2;
            uint4 v = *(const uint4*)(sp_ + (size_t)(rowb + rl)*256 + keff);
            if (neg) { v.x ^= 0x80008000u; v.y ^= 0x80008000u; v.z ^= 0x80008000u; v.w ^= 0x80008000u; }
            *(uint4*)(dst + rl*32 + kq) = v;
        }
        __syncthreads();

        short8 ah = *(const short8*)&sAh[(16*wv + l16)*32 + quad*8];
        short8 al = *(const short8*)&sAl[(16*wv + l16)*32 + quad*8];
#pragma unroll
        for (int ni = 0; ni < 4; ++ni) {
            short8 bh = *(const short8*)&sBh[(16*ni + l16)*32 + quad*8];
            short8 bl = *(const short8*)&sBl[(16*ni + l16)*32 + quad*8];
            acc[ni] = __builtin_amdgcn_mfma_f32_16x16x32_bf16(ah, bh, acc[ni], 0,0,0);
            acc[ni] = __builtin_amdgcn_mfma_f32_16x16x32_bf16(ah, bl, acc[ni], 0,0,0);
            acc[ni] = __builtin_amdgcn_mfma_f32_16x16x32_bf16(al, bh, acc[ni], 0,0,0);
        }
    }
#pragma unroll
    for (int ni = 0; ni < 4; ++ni)
#pragma unroll
        for (int rg = 0; rg < 4; ++rg) {
            int r = m0 + 16*wv + quad*4 + rg;
            int cc = n0 + 16*ni + l16;
            float v = acc[ni][rg];
            if (level < 2) {
                unsigned short h, l; bsplit(v, h, l);
                size_t off = (size_t)z*CMSZ + ((r < 256) ? ((size_t)r*256 + cc)
                                                         : (PLANE + (size_t)(r-256)*256 + cc));
                outH[off] = h; outL[off] = l;
            } else {
                unsigned short* bm = bmat + (size_t)z*MSZ;
                if (r < 256) {
                    unsigned short h = f2bf(v);
                    bm[(size_t)r*KDIM + cc] = h;
                    bm[(size_t)(r+256)*KDIM + cc + 256] = h;
                } else {
                    bm[(size_t)r*KDIM + cc] = f2bf(v);
                    bm[(size_t)(r-256)*KDIM + cc + 256] = f2bf(-v);
                }
            }
        }
}

// ---- batch GEMM tile: out[b][n] = sum_k x[b][k]*Bm[n][k], 64x128 tile ------
static __device__ void gemmTile(
    const unsigned short* __restrict__ A, const unsigned short* __restrict__ Bm,
    int mode, unsigned short* __restrict__ xout, float* __restrict__ Iout,
    int bx, int by, int vtid, unsigned short* smem)
{
    unsigned short* sA = smem;             // 64*32
    unsigned short* sB = smem + 2048;      // 128*32
    const int lane = vtid & 63, wv = vtid >> 6;
    const int quad = lane >> 4, l16 = lane & 15;
    const int m0 = bx * 64, n0 = by * 64;
    const int trowb = lane >> 2, tcol = (lane & 3) * 8;

    floatx4 acc[8] = {};
    for (int kt = 0; kt < KDIM; kt += 32) {
        __syncthreads();
        async16(A + (size_t)(m0 + 16*wv + trowb)*KDIM + kt + tcol,
                &sA[wv*512 + lane*8]);
#pragma unroll
        for (int j = 0; j < 2; ++j) {
            int trow = 32*wv + 16*j + trowb;
            int grow = (trow < 64) ? (n0 + trow) : (n0 + trow + 192);
            async16(Bm + (size_t)grow*KDIM + kt + tcol,
                    &sB[(32*wv + 16*j)*32 + lane*8]);
        }
        __syncthreads();
        short8 a = *(const short8*)&sA[(16*wv + l16)*32 + quad*8];
#pragma unroll
        for (int ni = 0; ni < 8; ++ni) {
            short8 b = *(const short8*)&sB[(16*ni + l16)*32 + quad*8];
            acc[ni] = __builtin_amdgcn_mfma_f32_16x16x32_bf16(a, b, acc[ni], 0,0,0);
        }
    }
#pragma unroll
    for (int ni = 0; ni < 4; ++ni)
#pragma unroll
        for (int rg = 0; rg < 4; ++rg) {
            int row = m0 + 16*wv + quad*4 + rg;
            int cc  = n0 + 16*ni + l16;
            float yr = acc[ni][rg], yi = acc[ni+4][rg];
            if (mode == 2) {
                Iout[(size_t)row*256 + cc] = yr*yr + yi*yi;
            } else {
                float I = yr*yr + yi*yi;
                float phase = 0.078539816339744831f * I + 1.5707963267948966f;
                float sp, cp; __sincosf(phase, &sp, &cp);
                float f = 0.94868329805051381f * cp;
                xout[(size_t)row*KDIM + cc]       = f2bf(f*(cp*yr + sp*yi));
                xout[(size_t)row*KDIM + cc + 256] = f2bf(f*(cp*yi - sp*yr));
            }
        }
}

// ---------------- standalone kernels (optimal grid per phase) ---------------

__global__ __launch_bounds__(256, 2) void k_prop(
    const float* __restrict__ xre, const float* __restrict__ xim,
    const float* __restrict__ theta, const float* __restrict__ phi,
    const float* __restrict__ gamma, char* __restrict__ ws)
{
    phaseProp(blockIdx.x, threadIdx.x, xre, xim, theta, phi, gamma,
              (unsigned short*)(ws + OFF_CHUNKH), (unsigned short*)(ws + OFF_CHUNKL),
              (unsigned short*)(ws + OFF_XBUF0));
}

__global__ __launch_bounds__(256, 2) void k_compose(
    char* __restrict__ ws, int level)
{
    __shared__ unsigned short smem[8192];
    const int vb = blockIdx.x;
    if (level == 0)
        composeTile((unsigned short*)(ws + OFF_CHUNKH), (unsigned short*)(ws + OFF_CHUNKL),
                    (unsigned short*)(ws + OFF_TH), (unsigned short*)(ws + OFF_TL),
                    nullptr, 0, vb >> 5, (vb >> 2) & 7, vb & 3, threadIdx.x, smem);
    else if (level == 1)
        composeTile((unsigned short*)(ws + OFF_TH), (unsigned short*)(ws + OFF_TL),
                    (unsigned short*)(ws + OFF_PH), (unsigned short*)(ws + OFF_PL),
                    nullptr, 1, vb >> 5, (vb >> 2) & 7, vb & 3, threadIdx.x, smem);
    else
        composeTile((unsigned short*)(ws + OFF_PH), (unsigned short*)(ws + OFF_PL),
                    nullptr, nullptr, (unsigned short*)(ws + OFF_BMAT),
                    2, vb >> 5, (vb >> 2) & 7, vb & 3, threadIdx.x, smem);
}

__global__ __launch_bounds__(256, 2) void k_gemm(
    char* __restrict__ ws, int mode)
{
    __shared__ unsigned short smem[6144];
    const int vb = blockIdx.x;
    unsigned short* xbuf0 = (unsigned short*)(ws + OFF_XBUF0);
    unsigned short* xbuf1 = (unsigned short*)(ws + OFF_XBUF1);
    unsigned short* bmat  = (unsigned short*)(ws + OFF_BMAT);
    float* Ibuf = (float*)(ws + OFF_IBUF);
    if (mode == 0)
        gemmTile(xbuf0, bmat,         0, xbuf1, nullptr, vb >> 2, vb & 3, threadIdx.x, smem);
    else if (mode == 1)
        gemmTile(xbuf1, bmat + MSZ,   1, xbuf0, nullptr, vb >> 2, vb & 3, threadIdx.x, smem);
    else
        gemmTile(xbuf0, bmat + 2*MSZ, 2, nullptr, Ibuf,  vb >> 2, vb & 3, threadIdx.x, smem);
}

__global__ __launch_bounds__(256, 2) void k_final(
    const char* __restrict__ ws, float* __restrict__ out)
{
    const float* Ibuf = (const float*)(ws + OFF_IBUF);
    const int lane = threadIdx.x & 63, vwv = threadIdx.x >> 6;
#pragma unroll
    for (int rep = 0; rep < 4; ++rep) {
        int row = blockIdx.x*16 + vwv*4 + rep;
        float4 v = *(const float4*)(Ibuf + (size_t)row * 256 + 4*lane);
        float ss = v.x*v.x + v.y*v.y + v.z*v.z + v.w*v.w;
#pragma unroll
        for (int d = 1; d < 64; d <<= 1) ss += __shfl_xor(ss, d, 64);
        float inv = 1.0f / fmaxf(sqrtf(ss), 1e-12f);
        float* o = out + (size_t)row * 10;
        if (lane == 0)      { o[0]=v.x*inv; o[1]=v.y*inv; o[2]=v.z*inv; o[3]=v.w*inv; }
        else if (lane == 1) { o[4]=v.x*inv; o[5]=v.y*inv; o[6]=v.z*inv; o[7]=v.w*inv; }
        else if (lane == 2) { o[8]=v.x*inv; o[9]=v.y*inv; }
    }
}

extern "C" void kernel_launch(void* const* d_in, const int* in_sizes, int n_in,
                              void* d_out, int out_size, void* d_ws, size_t ws_size,
                              hipStream_t stream)
{
    const float* x_real = (const float*)d_in[0];
    const float* x_imag = (const float*)d_in[1];
    const float* theta  = (const float*)d_in[2];
    const float* phi    = (const float*)d_in[3];
    const float* gamma  = (const float*)d_in[4];
    char* ws = (char*)d_ws;

    k_prop<<<512, 256, 0, stream>>>(x_real, x_imag, theta, phi, gamma, ws);
    k_compose<<<384, 256, 0, stream>>>(ws, 0);
    k_compose<<<192, 256, 0, stream>>>(ws, 1);
    k_compose<<<96,  256, 0, stream>>>(ws, 2);
    k_gemm<<<512, 256, 0, stream>>>(ws, 0);
    k_gemm<<<512, 256, 0, stream>>>(ws, 1);
    k_gemm<<<512, 256, 0, stream>>>(ws, 2);
    k_final<<<512, 256, 0, stream>>>(ws, (float*)d_out);
}

// Round 9
// 211.454 us; speedup vs baseline: 1.2292x; 1.0169x over previous
//
#include <hip/hip_runtime.h>
#include <hip/hip_cooperative_groups.h>
#include <math.h>

namespace cg = cooperative_groups;

#define NWG 256
#define NPAIR 128
#define NITER 3
#define NBATCH 8192
#define KDIM 512
#define MSZ (512*512)
#define PLANE 65536
#define CMSZ (2*PLANE)

// ws byte offsets — peak 27,262,976 B (proven safe R7/R8)
#define OFF_XBUF0   0u          // 8 MB
#define OFF_CHUNKH  8388608u    // 6 MB
#define OFF_CHUNKL  14680064u   // 6 MB
#define OFF_TH      20971520u   // 3 MB
#define OFF_TL      24117248u   // 3 MB
#define OFF_PH      8388608u    // 1.5MB (alias chunkH, dead)
#define OFF_PL      9961472u    // 1.5MB
#define OFF_BMAT    11534336u   // 1.5MB
#define OFF_XBUF1   13107200u   // 8 MB
#define OFF_IBUF    13107200u   // 8 MB (alias xbuf1, dead)

typedef __attribute__((ext_vector_type(8))) short short8;
typedef __attribute__((ext_vector_type(4))) float floatx4;

static __device__ __forceinline__ unsigned short f2bf(float f) {
    unsigned int u = __float_as_uint(f);
    unsigned int r = (u + 0x7fffu + ((u >> 16) & 1u)) >> 16;
    return (unsigned short)r;
}
static __device__ __forceinline__ float bf2f(unsigned short h) {
    return __uint_as_float(((unsigned int)h) << 16);
}
static __device__ __forceinline__ void bsplit(float v, unsigned short &h, unsigned short &l) {
    h = f2bf(v);
    l = f2bf(v - bf2f(h));
}
static __device__ __forceinline__ void async16(const void* g, void* l) {
    __builtin_amdgcn_global_load_lds(
        (const __attribute__((address_space(1))) unsigned int*)g,
        (__attribute__((address_space(3))) unsigned int*)l, 16, 0, 0);
}

static __device__ __forceinline__ void apply2(
    float &x0r, float &x0i, float &x1r, float &x1i,
    const float4 a, const float4 b)
{
    float y0r = a.x*x0r - a.y*x0i + a.z*x1r - a.w*x1i;
    float y0i = a.x*x0i + a.y*x0r + a.z*x1i + a.w*x1r;
    float y1r = b.x*x0r - b.y*x0i + b.z*x1r - b.w*x1i;
    float y1i = b.x*x0i + b.y*x0r + b.z*x1i + b.w*x1r;
    x0r = y0r; x0i = y0i; x1r = y1r; x1i = y1i;
}

static __device__ __forceinline__ void makeCoef(float th, float ph, bool rev,
                                                float4 &ca, float4 &cb) {
    float h  = 0.5f * th;
    float sh = __sinf(h),  ch = __cosf(h);
    float sp = __sinf(ph), cp = __cosf(ph);
    float pr = -sh, pi = ch;                 // pre = i*exp(i*h)
    float qr = pr*cp - pi*sp, qi = pr*sp + pi*cp;
    float Ar = qr*sh, Ai = qi*sh, Br = pr*ch, Bi = pi*ch;
    float Cr = qr*ch, Ci = qi*ch, Dr = -pr*sh, Di = -pi*sh;
    if (!rev) { ca = make_float4(Ar,Ai,Br,Bi); cb = make_float4(Cr,Ci,Dr,Di); }
    else      { ca = make_float4(Ar,Ai,Cr,Ci); cb = make_float4(Br,Bi,Dr,Di); }
}

// ---- propagate: 24 groups x 32 blocks, 32 layers, 2 rows/wave --------------
__global__ __launch_bounds__(256, 2) void k_prop(
    const float* __restrict__ theta, const float* __restrict__ phi,
    const float* __restrict__ gamma, char* __restrict__ ws)
{
    unsigned short* chunkH = (unsigned short*)(ws + OFF_CHUNKH);
    unsigned short* chunkL = (unsigned short*)(ws + OFF_CHUNKL);
    const int vtid = threadIdx.x;
    const int lane = vtid & 63, vwv = vtid >> 6;
    const int vb = blockIdx.x;                 // 0..767
    const int grp = vb >> 5, rb = vb & 31;     // 24 groups x 32 blocks
    const int it = grp >> 3, c = grp & 7;
    const bool rev = (c & 1);
    const int r0 = rb*8 + vwv*2;               // 2 rows per wave

    float xr[2][4], xi[2][4];
#pragma unroll
    for (int r = 0; r < 2; ++r) {
        float gc = 1.0f, gs = 0.0f;
        if (c == 7) {
            float g = gamma[it*NWG + r0 + r];
            gc = __cosf(g); gs = __sinf(g);
        }
#pragma unroll
        for (int e = 0; e < 4; ++e) {
            bool on = (4*lane + e) == (r0 + r);
            xr[r][e] = on ? gc : 0.0f;
            xi[r][e] = on ? gs : 0.0f;
        }
    }

    const float* thb = theta + (size_t)(it*NWG + c*32) * NPAIR;
    const float* phb = phi   + (size_t)(it*NWG + c*32) * NPAIR;
    int sp0 = rev ? 31 : 0;
    float2 t01 = *(const float2*)(thb + sp0*NPAIR + 2*lane);
    float2 p01 = *(const float2*)(phb + sp0*NPAIR + 2*lane);

    for (int s = 0; s < 32; ++s) {
        int sn  = (s + 1 < 32) ? s + 1 : s;
        int spn = rev ? 31 - sn : sn;
        float2 t01n = *(const float2*)(thb + spn*NPAIR + 2*lane);
        float2 p01n = *(const float2*)(phb + spn*NPAIR + 2*lane);

        float4 c0a, c0b, c1a, c1b;
        makeCoef(t01.x, p01.x, rev, c0a, c0b);
        makeCoef(t01.y, p01.y, rev, c1a, c1b);

        int sp = rev ? 31 - s : s;
        if ((sp & 1) == 0) {
#pragma unroll
            for (int r = 0; r < 2; ++r) {
                apply2(xr[r][0], xi[r][0], xr[r][1], xi[r][1], c0a, c0b);
                apply2(xr[r][2], xi[r][2], xr[r][3], xi[r][3], c1a, c1b);
            }
        } else {
#pragma unroll
            for (int r = 0; r < 2; ++r) {
                float tr = __shfl_down(xr[r][0], 1, 64);
                float ti = __shfl_down(xi[r][0], 1, 64);
                apply2(xr[r][1], xi[r][1], xr[r][2], xi[r][2], c0a, c0b);
                float x3r = xr[r][3], x3i = xi[r][3];
                float y3r = c1a.x*x3r - c1a.y*x3i + c1a.z*tr - c1a.w*ti;
                float y3i = c1a.x*x3i + c1a.y*x3r + c1a.z*ti + c1a.w*tr;
                float ynr = c1b.x*x3r - c1b.y*x3i + c1b.z*tr - c1b.w*ti;
                float yni = c1b.x*x3i + c1b.y*x3r + c1b.z*ti + c1b.w*tr;
                float rr = __shfl_up(ynr, 1, 64);
                float ri = __shfl_up(yni, 1, 64);
                if (lane != 63) { xr[r][3] = y3r; xi[r][3] = y3i; }
                if (lane != 0)  { xr[r][0] = rr;  xi[r][0] = ri; }
            }
        }
        t01 = t01n; p01 = p01n;
    }

    unsigned short* bh = chunkH + (size_t)grp * CMSZ;
    unsigned short* bl = chunkL + (size_t)grp * CMSZ;
#pragma unroll
    for (int r = 0; r < 2; ++r) {
        int rowIdx = r0 + r;
        ushort4 reH, reL, imH, imL;
        unsigned short h, l;
#pragma unroll
        for (int e = 0; e < 4; ++e) {
            bsplit(xr[r][e], h, l); ((unsigned short*)&reH)[e] = h; ((unsigned short*)&reL)[e] = l;
            bsplit(xi[r][e], h, l); ((unsigned short*)&imH)[e] = h; ((unsigned short*)&imL)[e] = l;
        }
        *(ushort4*)(bh + (size_t)rowIdx*256 + 4*lane)         = reH;
        *(ushort4*)(bh + PLANE + (size_t)rowIdx*256 + 4*lane) = imH;
        *(ushort4*)(bl + (size_t)rowIdx*256 + 4*lane)         = reL;
        *(ushort4*)(bl + PLANE + (size_t)rowIdx*256 + 4*lane) = imL;
    }
}

// ---- compose: C = Sa * Sb^T (complex, real-embedded at staging) ------------
static __device__ void composeTile(
    const unsigned short* __restrict__ srcH, const unsigned short* __restrict__ srcL,
    unsigned short* __restrict__ outH, unsigned short* __restrict__ outL,
    unsigned short* __restrict__ bmat, int level, int z, int bx, int by,
    int vtid, unsigned short* smem)
{
    unsigned short* sAh = smem;
    unsigned short* sAl = smem + 2048;
    unsigned short* sBh = smem + 4096;
    unsigned short* sBl = smem + 6144;
    int ai, bi;
    if (level == 0) {
        const int amap[4] = {0,3,4,7}, bmap[4] = {1,2,5,6};
        int it = z >> 2, j = z & 3;
        ai = it*8 + amap[j]; bi = it*8 + bmap[j];
    } else if (level == 1) {
        int it = z >> 1, wh = z & 1;
        ai = it*4 + (wh ? 3 : 0); bi = it*4 + (wh ? 2 : 1);
    } else {
        ai = 2*z + 1; bi = 2*z;
    }
    const int lane = vtid & 63, wv = vtid >> 6;
    const int quad = lane >> 4, l16 = lane & 15;
    const int m0 = bx * 64;
    const int n0 = by * 64;
    const bool isA = (wv < 2);
    const unsigned short* mat = ((wv & 1) ? srcL : srcH) + (size_t)(isA ? ai : bi) * CMSZ;
    unsigned short* dst = (wv==0)?sAh:(wv==1)?sAl:(wv==2)?sBh:sBl;
    const int l2 = lane >> 2, kq = (lane & 3) * 8;
    const int rowb = isA ? ((m0 < 256) ? m0 : m0 - 256) : n0;

    floatx4 acc[4] = {};
    for (int kt = 0; kt < KDIM; kt += 32) {
        int po; bool neg = false;
        if (kt < 256) po = (isA && m0 >= 256) ? PLANE : 0;
        else {
            if (isA) { if (m0 < 256) { po = PLANE; neg = true; } else po = 0; }
            else po = PLANE;
        }
        int keff = (kt < 256 ? kt : kt - 256) + kq;
        const unsigned short* sp_ = mat + po;

        __syncthreads();
#pragma unroll
        for (int i = 0; i < 4; ++i) {
            int rl = i*16 + l2;
            uint4 v = *(const uint4*)(sp_ + (size_t)(rowb + rl)*256 + keff);
            if (neg) { v.x ^= 0x80008000u; v.y ^= 0x80008000u; v.z ^= 0x80008000u; v.w ^= 0x80008000u; }
            *(uint4*)(dst + rl*32 + kq) = v;
        }
        __syncthreads();

        short8 ah = *(const short8*)&sAh[(16*wv + l16)*32 + quad*8];
        short8 al = *(const short8*)&sAl[(16*wv + l16)*32 + quad*8];
#pragma unroll
        for (int ni = 0; ni < 4; ++ni) {
            short8 bh = *(const short8*)&sBh[(16*ni + l16)*32 + quad*8];
            short8 bl = *(const short8*)&sBl[(16*ni + l16)*32 + quad*8];
            acc[ni] = __builtin_amdgcn_mfma_f32_16x16x32_bf16(ah, bh, acc[ni], 0,0,0);
            acc[ni] = __builtin_amdgcn_mfma_f32_16x16x32_bf16(ah, bl, acc[ni], 0,0,0);
            acc[ni] = __builtin_amdgcn_mfma_f32_16x16x32_bf16(al, bh, acc[ni], 0,0,0);
        }
    }
#pragma unroll
    for (int ni = 0; ni < 4; ++ni)
#pragma unroll
        for (int rg = 0; rg < 4; ++rg) {
            int r = m0 + 16*wv + quad*4 + rg;
            int cc = n0 + 16*ni + l16;
            float v = acc[ni][rg];
            if (level < 2) {
                unsigned short h, l; bsplit(v, h, l);
                size_t off = (size_t)z*CMSZ + ((r < 256) ? ((size_t)r*256 + cc)
                                                         : (PLANE + (size_t)(r-256)*256 + cc));
                outH[off] = h; outL[off] = l;
            } else {
                unsigned short* bm = bmat + (size_t)z*MSZ;
                if (r < 256) {
                    unsigned short h = f2bf(v);
                    bm[(size_t)r*KDIM + cc] = h;
                    bm[(size_t)(r+256)*KDIM + cc + 256] = h;
                } else {
                    bm[(size_t)r*KDIM + cc] = f2bf(v);
                    bm[(size_t)(r-256)*KDIM + cc + 256] = f2bf(-v);
                }
            }
        }
}

// ---- batch GEMM tile: out[b][n] = sum_k x[b][k]*Bm[n][k], 64x128 tile ------
static __device__ void gemmTile(
    const unsigned short* __restrict__ A, const unsigned short* __restrict__ Bm,
    int mode, unsigned short* __restrict__ xout, float* __restrict__ Iout,
    int bx, int by, int vtid, unsigned short* smem)
{
    unsigned short* sA = smem;             // 64*32
    unsigned short* sB = smem + 2048;      // 128*32
    const int lane = vtid & 63, wv = vtid >> 6;
    const int quad = lane >> 4, l16 = lane & 15;
    const int m0 = bx * 64, n0 = by * 64;
    const int trowb = lane >> 2, tcol = (lane & 3) * 8;

    floatx4 acc[8] = {};
    for (int kt = 0; kt < KDIM; kt += 32) {
        __syncthreads();
        async16(A + (size_t)(m0 + 16*wv + trowb)*KDIM + kt + tcol,
                &sA[wv*512 + lane*8]);
#pragma unroll
        for (int j = 0; j < 2; ++j) {
            int trow = 32*wv + 16*j + trowb;
            int grow = (trow < 64) ? (n0 + trow) : (n0 + trow + 192);
            async16(Bm + (size_t)grow*KDIM + kt + tcol,
                    &sB[(32*wv + 16*j)*32 + lane*8]);
        }
        __syncthreads();
        short8 a = *(const short8*)&sA[(16*wv + l16)*32 + quad*8];
#pragma unroll
        for (int ni = 0; ni < 8; ++ni) {
            short8 b = *(const short8*)&sB[(16*ni + l16)*32 + quad*8];
            acc[ni] = __builtin_amdgcn_mfma_f32_16x16x32_bf16(a, b, acc[ni], 0,0,0);
        }
    }
#pragma unroll
    for (int ni = 0; ni < 4; ++ni)
#pragma unroll
        for (int rg = 0; rg < 4; ++rg) {
            int row = m0 + 16*wv + quad*4 + rg;
            int cc  = n0 + 16*ni + l16;
            float yr = acc[ni][rg], yi = acc[ni+4][rg];
            if (mode == 2) {
                Iout[(size_t)row*256 + cc] = yr*yr + yi*yi;
            } else {
                float I = yr*yr + yi*yi;
                float phase = 0.078539816339744831f * I + 1.5707963267948966f;
                float sp, cp; __sincosf(phase, &sp, &cp);
                float f = 0.94868329805051381f * cp;
                xout[(size_t)row*KDIM + cc]       = f2bf(f*(cp*yr + sp*yi));
                xout[(size_t)row*KDIM + cc + 256] = f2bf(f*(cp*yi - sp*yr));
            }
        }
}

static __device__ void convertChunk(int vb, int vtid,
                                    const float* __restrict__ xre,
                                    const float* __restrict__ xim,
                                    unsigned short* __restrict__ xbuf0)
{
    int base = (vb - 384) * 64;            // 128 blocks x 64 units = 8192
    for (int u = 0; u < 64; ++u) {
        int unit = base + u;
        xbuf0[(size_t)unit * KDIM + vtid]       = f2bf(xre[(size_t)unit * NWG + vtid]);
        xbuf0[(size_t)unit * KDIM + 256 + vtid] = f2bf(xim[(size_t)unit * NWG + vtid]);
    }
}

static __device__ void phaseFinal(int vb, int vtid,
                                  const float* __restrict__ Ibuf,
                                  float* __restrict__ out)
{
    const int lane = vtid & 63, vwv = vtid >> 6;
#pragma unroll
    for (int rep = 0; rep < 4; ++rep) {
        int row = vb*16 + vwv*4 + rep;
        float4 v = *(const float4*)(Ibuf + (size_t)row * 256 + 4*lane);
        float ss = v.x*v.x + v.y*v.y + v.z*v.z + v.w*v.w;
#pragma unroll
        for (int d = 1; d < 64; d <<= 1) ss += __shfl_xor(ss, d, 64);
        float inv = 1.0f / fmaxf(sqrtf(ss), 1e-12f);
        float* o = out + (size_t)row * 10;
        if (lane == 0)      { o[0]=v.x*inv; o[1]=v.y*inv; o[2]=v.z*inv; o[3]=v.w*inv; }
        else if (lane == 1) { o[4]=v.x*inv; o[5]=v.y*inv; o[6]=v.z*inv; o[7]=v.w*inv; }
        else if (lane == 2) { o[8]=v.x*inv; o[9]=v.y*inv; }
    }
}

static __device__ __forceinline__ void do_phase(
    int ph, int vb, int vtid, unsigned short* smem,
    const float* xre, const float* xim, char* ws, float* out)
{
    unsigned short* xbuf0  = (unsigned short*)(ws + OFF_XBUF0);
    unsigned short* chunkH = (unsigned short*)(ws + OFF_CHUNKH);
    unsigned short* chunkL = (unsigned short*)(ws + OFF_CHUNKL);
    unsigned short* TH     = (unsigned short*)(ws + OFF_TH);
    unsigned short* TL     = (unsigned short*)(ws + OFF_TL);
    unsigned short* PH     = (unsigned short*)(ws + OFF_PH);
    unsigned short* PL     = (unsigned short*)(ws + OFF_PL);
    unsigned short* bmat   = (unsigned short*)(ws + OFF_BMAT);
    unsigned short* xbuf1  = (unsigned short*)(ws + OFF_XBUF1);
    float*          Ibuf   = (float*)(ws + OFF_IBUF);

    switch (ph) {
    case 0:
        if (vb < 384) composeTile(chunkH, chunkL, TH, TL, nullptr, 0,
                                  vb >> 5, (vb >> 2) & 7, vb & 3, vtid, smem);
        else convertChunk(vb, vtid, xre, xim, xbuf0);
        break;
    case 1: if (vb < 192) composeTile(TH, TL, PH, PL, nullptr, 1,
                                      vb >> 5, (vb >> 2) & 7, vb & 3, vtid, smem); break;
    case 2: if (vb < 96)  composeTile(PH, PL, nullptr, nullptr, bmat, 2,
                                      vb >> 5, (vb >> 2) & 7, vb & 3, vtid, smem); break;
    case 3: gemmTile(xbuf0, bmat,         0, xbuf1, nullptr, vb >> 2, vb & 3, vtid, smem); break;
    case 4: gemmTile(xbuf1, bmat + MSZ,   1, xbuf0, nullptr, vb >> 2, vb & 3, vtid, smem); break;
    case 5: gemmTile(xbuf0, bmat + 2*MSZ, 2, nullptr, Ibuf,  vb >> 2, vb & 3, vtid, smem); break;
    case 6: phaseFinal(vb, vtid, Ibuf, out); break;
    }
}

__global__ __launch_bounds__(256, 2) void coop_kernel(
    const float* __restrict__ xre, const float* __restrict__ xim,
    char* __restrict__ ws, float* __restrict__ out)
{
    __shared__ unsigned short smem[8192];
    cg::grid_group grid = cg::this_grid();
    for (int ph = 0; ph < 7; ++ph) {
        do_phase(ph, blockIdx.x, threadIdx.x, smem, xre, xim, ws, out);
        if (ph < 6) grid.sync();
    }
}

// fallback: one phase per plain launch
__global__ __launch_bounds__(256, 2) void phase_kernel(
    int ph, const float* __restrict__ xre, const float* __restrict__ xim,
    char* __restrict__ ws, float* __restrict__ out)
{
    __shared__ unsigned short smem[8192];
    do_phase(ph, blockIdx.x, threadIdx.x, smem, xre, xim, ws, out);
}

extern "C" void kernel_launch(void* const* d_in, const int* in_sizes, int n_in,
                              void* d_out, int out_size, void* d_ws, size_t ws_size,
                              hipStream_t stream)
{
    const float* x_real = (const float*)d_in[0];
    const float* x_imag = (const float*)d_in[1];
    const float* theta  = (const float*)d_in[2];
    const float* phi    = (const float*)d_in[3];
    const float* gamma  = (const float*)d_in[4];
    char* ws = (char*)d_ws;
    float* outp = (float*)d_out;

    k_prop<<<768, 256, 0, stream>>>(theta, phi, gamma, ws);

    // need 2 co-resident blocks/CU for the 512-block cooperative grid
    int maxBlocks = 0;
    hipError_t qerr = hipOccupancyMaxActiveBlocksPerMultiprocessor(
        &maxBlocks, (const void*)coop_kernel, 256, 0);

    if (qerr == hipSuccess && maxBlocks >= 2) {
        void* args[] = { (void*)&x_real, (void*)&x_imag, (void*)&ws, (void*)&outp };
        hipLaunchCooperativeKernel((void*)coop_kernel, dim3(512), dim3(256),
                                   args, 0, stream);
    } else {
        for (int ph = 0; ph < 7; ++ph)
            phase_kernel<<<512, 256, 0, stream>>>(ph, x_real, x_imag, ws, outp);
    }
}